// Round 6
// baseline (154.709 us; speedup 1.0000x reference)
//
#include <hip/hip_runtime.h>
#include <hip/hip_bf16.h>
#include <math.h>

#define ICH   3
#define OCH   16
#define ID    18
#define IH    34
#define IW    34
#define OD    16
#define OH    32
#define OW    32
#define NB    128
#define SPATIAL  (OD * OH * OW)     // 16384 per (b,c)
#define EPSV     1e-5f

typedef __fp16 fp16x2 __attribute__((ext_vector_type(2)));

#if __has_builtin(__builtin_elementwise_fma)
#define FMA2(a_, b_, c_) __builtin_elementwise_fma((a_), (b_), (c_))
#else
#define FMA2(a_, b_, c_) ((a_) * (b_) + (c_))   // -ffp-contract fuses to v_pk_fma_f16
#endif

// Budget model (R3-R5): conv busy ~40us VALU-ISSUE-bound (fdot2 measured
// HALF-RATE on gfx950 -> R5 only +3us); conv idle ~20us structural
// (occupancy-independent, R4); norm 11us = BW roofline; fixed harness ~67us.
// This round: v_pk_fma_f16 (VOP3P, full-rate, 2 fp16 MACs / 2cyc inst),
// two OUTPUT POSITIONS packed per register, per-ic fp16 chains (27 MACs)
// widened into fp32 accs -> busy model 40 -> ~25us.

// Pre-pass: wd[tap][c] = fp16x2(w, w) (duplicated halves), tap = ic*27+kd*9+kh*3+kw.
__global__ void transpose_w_kernel(const float* __restrict__ cw,
                                   unsigned int* __restrict__ wd) {
    const int i = blockIdx.x * 256 + threadIdx.x;   // 0..1295
    if (i < 81 * OCH) {
        const int t = i >> 4;      // tap 0..80
        const int c = i & 15;
        const __fp16 h = (__fp16)cw[c * 81 + t];    // OIDHW: per-oc stride 81
        fp16x2 hv; hv.x = h; hv.y = h;
        union { fp16x2 h2; unsigned int u; } uu; uu.h2 = hv;
        wd[t * OCH + c] = uu.u;
    }
}

// ===== conv v12: pk_fma conv. 16 ch/block, grid 2048, LB(256,2), channel-
// major y (best-known settings). Inner math per (ic,kd,kh,kw,c):
//   a16[c][0] = pk_fma(p[kw],   wdup, a16[c][0])   // outputs j=0,1
//   a16[c][1] = pk_fma(p[kw+2], wdup, a16[c][1])   // outputs j=2,3
// where p[s] = cvt_pkrtz(in[s], in[s+1]). fp16 chains span one ic (27 MACs),
// widened to fp32 accF between ics (err ~2e-3 << 0.0156 y-quant floor).
// Do NOT: LDS-stage x (R1-R8), MFMA im2col (R13), occupancy pushes (R4),
// channel-last y (R2: +4.3us), v_dot2 (R5: half-rate).
__global__ __launch_bounds__(256, 2) void conv_stats_kernel(
    const float* __restrict__ x, const unsigned int* __restrict__ wd,
    const float* __restrict__ cb, const float* __restrict__ mult,
    unsigned short* __restrict__ y, float* __restrict__ stats)
{
    __shared__ float wsum[4][OCH], wsq[4][OCH];

    const int blk = blockIdx.x;
    const int b = blk >> 4;
    const int d = blk & 15;
    const int tid = threadIdx.x;

    const int h  = tid >> 3;        // 0..31
    const int wq = (tid & 7) << 2;  // 0,4,...,28

    float accF[OCH][4];
#pragma unroll
    for (int c = 0; c < OCH; c++) {
        const float bv = cb[c];
        accF[c][0] = bv; accF[c][1] = bv; accF[c][2] = bv; accF[c][3] = bv;
    }

    for (int ic = 0; ic < ICH; ic++) {
        fp16x2 a16[OCH][2];
#pragma unroll
        for (int c = 0; c < OCH; c++) {
            a16[c][0] = (fp16x2)0.0f;
            a16[c][1] = (fp16x2)0.0f;
        }

#pragma unroll
        for (int kd = 0; kd < 3; kd++) {
            const float* plane = x + ((size_t)(b * ICH + ic) * ID + (d + kd)) * (IH * IW);
            const unsigned int* wg = wd + (ic * 27 + kd * 9) * OCH;
#pragma unroll
            for (int kh = 0; kh < 3; kh++) {
                const float* row = plane + (size_t)(h + kh) * IW + wq;
                const float4 v0 = *(const float4*)row;
                const float2 v1 = *(const float2*)(row + 4);
                fp16x2 p[5];                        // p[s] = (in[s], in[s+1])
                p[0] = __builtin_amdgcn_cvt_pkrtz(v0.x, v0.y);
                p[1] = __builtin_amdgcn_cvt_pkrtz(v0.y, v0.z);
                p[2] = __builtin_amdgcn_cvt_pkrtz(v0.z, v0.w);
                p[3] = __builtin_amdgcn_cvt_pkrtz(v0.w, v1.x);
                p[4] = __builtin_amdgcn_cvt_pkrtz(v1.x, v1.y);
                const unsigned int* wrow = wg + kh * 3 * OCH;
#pragma unroll
                for (int kw = 0; kw < 3; kw++) {
#pragma unroll
                    for (int c = 0; c < OCH; c++) {
                        union { unsigned int u; fp16x2 h2; } wv;
                        wv.u = wrow[kw * OCH + c];          // s_load path
                        a16[c][0] = FMA2(p[kw],     wv.h2, a16[c][0]);
                        a16[c][1] = FMA2(p[kw + 2], wv.h2, a16[c][1]);
                    }
                }
            }
        }

        // widen per-ic fp16 partials into fp32 accumulators
#pragma unroll
        for (int c = 0; c < OCH; c++) {
            accF[c][0] += (float)a16[c][0].x;
            accF[c][1] += (float)a16[c][0].y;
            accF[c][2] += (float)a16[c][1].x;
            accF[c][3] += (float)a16[c][1].y;
        }
    }

    // ---- multiplier fold, stats, fp16 store (channel-major, uint2) ----
    float ssum[OCH], ssq[OCH];
#pragma unroll
    for (int c = 0; c < OCH; c++) {
        const float m = mult[c];
        const float o0 = accF[c][0] * m, o1 = accF[c][1] * m;
        const float o2 = accF[c][2] * m, o3 = accF[c][3] * m;
        ssum[c] = (o0 + o1) + (o2 + o3);
        ssq[c]  = (o0 * o0 + o1 * o1) + (o2 * o2 + o3 * o3);
        const size_t yi = ((size_t)(b * OCH + c) * OD + d) * (OH * OW) + h * OW + wq;
        union { fp16x2 h; unsigned int u; } p01, p23;
        p01.h = __builtin_amdgcn_cvt_pkrtz(o0, o1);
        p23.h = __builtin_amdgcn_cvt_pkrtz(o2, o3);
        uint2 pk; pk.x = p01.u; pk.y = p23.u;
        *(uint2*)&y[yi] = pk;
    }

    // ---- block reduction of stats, per-block partial write (no atomics) ----
#pragma unroll
    for (int c = 0; c < OCH; c++) {
        for (int off = 32; off > 0; off >>= 1) {
            ssum[c] += __shfl_down(ssum[c], off);
            ssq[c]  += __shfl_down(ssq[c], off);
        }
    }
    const int wave = tid >> 6, lane = tid & 63;
    if (lane == 0) {
#pragma unroll
        for (int c = 0; c < OCH; c++) { wsum[wave][c] = ssum[c]; wsq[wave][c] = ssq[c]; }
    }
    __syncthreads();
    if (tid < OCH) {
        float s = 0.0f, q = 0.0f;
#pragma unroll
        for (int k = 0; k < 4; k++) { s += wsum[k][tid]; q += wsq[k][tid]; }
        const int sbase = ((b * OD + d) * OCH + tid) * 2;
        stats[sbase + 0] = s;
        stats[sbase + 1] = q;
    }
}

// ===== per-(b,c) norm params: {A = rs*m, B = -mean*rs*m, L = -|m|, H = +|m|}
__global__ void params_kernel(const float* __restrict__ stats,
                              const float* __restrict__ mult,
                              float4* __restrict__ prm)
{
    const int i = blockIdx.x * 256 + threadIdx.x;   // (b,c) pair
    if (i < NB * OCH) {
        const int b = i >> 4, c = i & 15;
        float s = 0.0f, q = 0.0f;
        for (int dd = 0; dd < OD; dd++) {
            s += stats[((b * OD + dd) * OCH + c) * 2 + 0];
            q += stats[((b * OD + dd) * OCH + c) * 2 + 1];
        }
        const float mean = s * (1.0f / (float)SPATIAL);
        float var = q * (1.0f / (float)SPATIAL) - mean * mean;
        var = fmaxf(var, 0.0f);
        const float rs = rsqrtf(var + EPSV);
        const float m  = mult[c];
        float4 p;
        p.x = rs * m;             // A
        p.y = -mean * rs * m;     // B
        p.z = -fabsf(m);          // L
        p.w =  fabsf(m);          // H
        prm[i] = p;
    }
}

// ===== norm_max (R1 version, measured ~11us = BW roofline; do not touch).
__global__ __launch_bounds__(256, 4) void norm_max_kernel(
    const unsigned short* __restrict__ y, const float4* __restrict__ prm,
    float* __restrict__ out)
{
    const int blk = blockIdx.x;     // NB*8 = 1024
    const int b   = blk >> 3;
    const int seg = blk & 7;
    const int tid = threadIdx.x;

    const int s = seg * 2048 + tid * 8;                  // 8 positions
    const unsigned short* yb = y + (size_t)b * OCH * SPATIAL + s;

    uint4 v[OCH];
#pragma unroll
    for (int c = 0; c < OCH; c++) {
        v[c] = *(const uint4*)(yb + (size_t)c * SPATIAL);
    }

    const float4* pb = prm + b * OCH;

    float mx[8];
#pragma unroll
    for (int j = 0; j < 8; j++) mx[j] = -INFINITY;

#pragma unroll
    for (int c = 0; c < OCH; c++) {
        const float4 p = pb[c];          // wave-uniform addr
        const float A = p.x, Bv = p.y, L = p.z, H = p.w;
        union { uint4 u4; unsigned int u[4]; } vv; vv.u4 = v[c];
#pragma unroll
        for (int w = 0; w < 4; w++) {
            union { unsigned int u; __fp16 h[2]; } a; a.u = vv.u[w];
            float f0 = fmaf((float)a.h[0], A, Bv);
            float f1 = fmaf((float)a.h[1], A, Bv);
            f0 = fminf(fmaxf(f0, L), H);                 // v_med3_f32 idiom
            f1 = fminf(fmaxf(f1, L), H);
            mx[2 * w]     = fmaxf(mx[2 * w],     f0);
            mx[2 * w + 1] = fmaxf(mx[2 * w + 1], f1);
        }
    }

    float* ob = out + (size_t)b * SPATIAL + s;
    float4 o0, o1;
    o0.x = mx[0]; o0.y = mx[1]; o0.z = mx[2]; o0.w = mx[3];
    o1.x = mx[4]; o1.y = mx[5]; o1.z = mx[6]; o1.w = mx[7];
    *(float4*)ob       = o0;
    *(float4*)(ob + 4) = o1;
}

extern "C" void kernel_launch(void* const* d_in, const int* in_sizes, int n_in,
                              void* d_out, int out_size, void* d_ws, size_t ws_size,
                              hipStream_t stream) {
    const float* x    = (const float*)d_in[0];
    const float* cw   = (const float*)d_in[1];
    const float* cb   = (const float*)d_in[2];
    const float* mult = (const float*)d_in[3];
    float* out = (float*)d_out;

    // ws: y fp16 channel-major (64 MB) | stats partials (256 KB) | prm (8 KB) | wd (5.2 KB)
    unsigned short* y = (unsigned short*)d_ws;
    float* stats = (float*)((char*)d_ws + (size_t)NB * OCH * SPATIAL * sizeof(unsigned short));
    float4* prm  = (float4*)(stats + NB * OD * OCH * 2);
    unsigned int* wdp = (unsigned int*)(prm + NB * OCH);

    transpose_w_kernel<<<6, 256, 0, stream>>>(cw, wdp);
    conv_stats_kernel<<<NB * 16, 256, 0, stream>>>(x, wdp, cb, mult, y, stats);
    params_kernel<<<8, 256, 0, stream>>>(stats, mult, prm);
    norm_max_kernel<<<NB * 8, 256, 0, stream>>>(y, prm, out);
}

// Round 7
// 139.115 us; speedup vs baseline: 1.1121x; 1.1121x over previous
//
#include <hip/hip_runtime.h>
#include <hip/hip_bf16.h>
#include <math.h>

#define ICH   3
#define OCH   16
#define ID    18
#define IH    34
#define IW    34
#define OD    16
#define OH    32
#define OW    32
#define NB    128
#define SPATIAL  (OD * OH * OW)     // 16384 per (b,c)
#define EPSV     1e-5f

typedef __fp16 fp16x2 __attribute__((ext_vector_type(2)));

// Budget model (R3-R6): conv VALU-pipe busy ~40us is the non-MFMA MAC floor
// (confirmed 3x: fp32 fma, fdot2 half-rate, pk_fma_f16 half-rate+overhead
// REGRESSED R6). conv idle ~20us: occupancy-independent (R4) -> theory:
// exposed x-load latency + cross-XCD L2 scatter. norm 11us = BW roofline.
// Fixed harness ~65us. This round: XCD-local block remap + explicit
// double-buffered load pipeline on the R5 fdot2 conv.

// Pre-pass: pack weights into fp16 row-pairs: wp[p][kw][c] = (w[2p],w[2p+1])
// where row r = ic*9 + kd*3 + kh (0..26), r=27 -> 0. u32-packed half2.
__global__ void transpose_w_kernel(const float* __restrict__ cw,
                                   unsigned int* __restrict__ wp) {
    const int i = blockIdx.x * 256 + threadIdx.x;   // 0..671
    if (i < 14 * 48) {
        const int p = i / 48, rem = i - p * 48;
        const int kw = rem >> 4, c = rem & 15;
        const int r0 = 2 * p, r1 = 2 * p + 1;
        // cw is OIDHW: [oc][ic][kd][kh][kw]
        const int ic0 = r0 / 9, kd0 = (r0 / 3) % 3, kh0 = r0 % 3;
        float f0 = cw[((c * ICH + ic0) * 3 + kd0) * 9 + kh0 * 3 + kw];
        float f1 = 0.0f;
        if (r1 < 27) {
            const int ic1 = r1 / 9, kd1 = (r1 / 3) % 3, kh1 = r1 % 3;
            f1 = cw[((c * ICH + ic1) * 3 + kd1) * 9 + kh1 * 3 + kw];
        }
        fp16x2 hv; hv.x = (__fp16)f0; hv.y = (__fp16)f1;
        union { fp16x2 h; unsigned int u; } uu; uu.h = hv;
        wp[i] = uu.u;
    }
}

// ===== conv v13: R5 fdot2 math + (1) XCD-local remap: all 16 d-slices of a
// given b land on ONE XCD (blk = const mod 8) so kd-overlapping x planes
// (250 KB/b) are shared in that XCD's 4MB L2; (2) double-buffered pipeline:
// group g+1's 18 floats load while group g's 576 fdot2 run -> ~600cy cover
// per load batch. Do NOT: LDS-stage x (R1-R8), MFMA im2col (R13), occupancy
// pushes (R4: no effect), channel-last y (R2: +4.3us), pk_fma_f16 (R6:
// half-rate, regressed), fdot2 issue-halving hope (R5: half-RATE, no gain).
__global__ __launch_bounds__(256, 2) void conv_stats_kernel(
    const float* __restrict__ x, const unsigned int* __restrict__ wp,
    const float* __restrict__ cb, const float* __restrict__ mult,
    unsigned short* __restrict__ y, float* __restrict__ stats)
{
    __shared__ float wsum[4][OCH], wsq[4][OCH];

    const int blk = blockIdx.x;          // 0..2047
    const int x8  = blk & 7;             // XCD id under round-robin dispatch
    const int q   = blk >> 3;            // 0..255
    const int b   = x8 + 8 * (q >> 4);   // 0..127  (b mod 8 == XCD)
    const int d   = q & 15;
    const int tid = threadIdx.x;

    const int h  = tid >> 3;        // 0..31
    const int wq = (tid & 7) << 2;  // 0,4,...,28

    float acc[OCH][4];
#pragma unroll
    for (int c = 0; c < OCH; c++) {
        const float bv = cb[c];
        acc[c][0] = bv; acc[c][1] = bv; acc[c][2] = bv; acc[c][3] = bv;
    }

    // load the 3 rows (18 floats) of group g = ic*3+kd into buf_
#define LOADG(buf_, g_)                                                     \
    {                                                                       \
        const int ic_ = (g_) / 3, kd_ = (g_) % 3;                           \
        const float* plane_ = x + ((size_t)(b * ICH + ic_) * ID + (d + kd_)) * (IH * IW); \
        _Pragma("unroll")                                                   \
        for (int kh_ = 0; kh_ < 3; kh_++) {                                 \
            const float* row_ = plane_ + (size_t)(h + kh_) * IW + wq;       \
            const float4 v0_ = *(const float4*)row_;                        \
            const float2 v1_ = *(const float2*)(row_ + 4);                  \
            buf_[kh_ * 6 + 0] = v0_.x; buf_[kh_ * 6 + 1] = v0_.y;           \
            buf_[kh_ * 6 + 2] = v0_.z; buf_[kh_ * 6 + 3] = v0_.w;           \
            buf_[kh_ * 6 + 4] = v1_.x; buf_[kh_ * 6 + 5] = v1_.y;           \
        }                                                                   \
    }

    // one row-pair (float rows A_,B_): pack 6 cols as (A,B) fp16 pairs, then
    // 3kw x 16c x 4out fdot2 against duplicated-pair weights wp[p_].
#define PAIRF(A_, B_, p_)                                                   \
    {                                                                       \
        fp16x2 pk_[6];                                                      \
        _Pragma("unroll")                                                   \
        for (int j_ = 0; j_ < 6; j_++)                                      \
            pk_[j_] = __builtin_amdgcn_cvt_pkrtz((A_)[j_], (B_)[j_]);       \
        const unsigned int* wg_ = wp + (p_) * 48;                           \
        _Pragma("unroll")                                                   \
        for (int kw_ = 0; kw_ < 3; kw_++) {                                 \
            _Pragma("unroll")                                               \
            for (int c_ = 0; c_ < OCH; c_++) {                              \
                union { unsigned int u; fp16x2 h; } wv_;                    \
                wv_.u = wg_[kw_ * OCH + c_];                                \
                acc[c_][0] = __builtin_amdgcn_fdot2(pk_[kw_ + 0], wv_.h, acc[c_][0], false); \
                acc[c_][1] = __builtin_amdgcn_fdot2(pk_[kw_ + 1], wv_.h, acc[c_][1], false); \
                acc[c_][2] = __builtin_amdgcn_fdot2(pk_[kw_ + 2], wv_.h, acc[c_][2], false); \
                acc[c_][3] = __builtin_amdgcn_fdot2(pk_[kw_ + 3], wv_.h, acc[c_][3], false); \
            }                                                               \
        }                                                                   \
    }

    float buf[2][18];           // ping-pong group buffers (static idx: full unroll)
    float pend[6];
    LOADG(buf[0], 0)
#pragma unroll
    for (int g = 0; g < 9; g++) {
        const float* cur = buf[g & 1];
        if (g < 8) { LOADG(buf[(g + 1) & 1], g + 1) }   // prefetch next group
        const float* r0 = cur, *r1 = cur + 6, *r2 = cur + 12;
        if ((g & 1) == 0) {                  // compile-time parity
            PAIRF(r0, r1, (3 * g) / 2)
#pragma unroll
            for (int j = 0; j < 6; j++) pend[j] = r2[j];  // copy: survives buf reuse
        } else {
            PAIRF(pend, r0, (3 * g - 1) / 2)
            PAIRF(r1, r2, (3 * g + 1) / 2)
        }
    }
    {   // final pair: row 26 with zero row (p = 13)
        float rz[6];
#pragma unroll
        for (int j = 0; j < 6; j++) rz[j] = 0.0f;
        PAIRF(pend, rz, 13)
    }
#undef PAIRF
#undef LOADG

    // ---- multiplier fold, stats, fp16 store (channel-major, uint2) ----
    float ssum[OCH], ssq[OCH];
#pragma unroll
    for (int c = 0; c < OCH; c++) {
        const float m = mult[c];
        const float o0 = acc[c][0] * m, o1 = acc[c][1] * m;
        const float o2 = acc[c][2] * m, o3 = acc[c][3] * m;
        ssum[c] = (o0 + o1) + (o2 + o3);
        ssq[c]  = (o0 * o0 + o1 * o1) + (o2 * o2 + o3 * o3);
        const size_t yi = ((size_t)(b * OCH + c) * OD + d) * (OH * OW) + h * OW + wq;
        union { fp16x2 h; unsigned int u; } p01, p23;
        p01.h = __builtin_amdgcn_cvt_pkrtz(o0, o1);
        p23.h = __builtin_amdgcn_cvt_pkrtz(o2, o3);
        uint2 pk; pk.x = p01.u; pk.y = p23.u;
        *(uint2*)&y[yi] = pk;
    }

    // ---- block reduction of stats, per-block partial write (no atomics) ----
#pragma unroll
    for (int c = 0; c < OCH; c++) {
        for (int off = 32; off > 0; off >>= 1) {
            ssum[c] += __shfl_down(ssum[c], off);
            ssq[c]  += __shfl_down(ssq[c], off);
        }
    }
    const int wave = tid >> 6, lane = tid & 63;
    if (lane == 0) {
#pragma unroll
        for (int c = 0; c < OCH; c++) { wsum[wave][c] = ssum[c]; wsq[wave][c] = ssq[c]; }
    }
    __syncthreads();
    if (tid < OCH) {
        float s = 0.0f, q2 = 0.0f;
#pragma unroll
        for (int k = 0; k < 4; k++) { s += wsum[k][tid]; q2 += wsq[k][tid]; }
        const int sbase = ((b * OD + d) * OCH + tid) * 2;
        stats[sbase + 0] = s;
        stats[sbase + 1] = q2;
    }
}

// ===== per-(b,c) norm params: {A = rs*m, B = -mean*rs*m, L = -|m|, H = +|m|}
__global__ void params_kernel(const float* __restrict__ stats,
                              const float* __restrict__ mult,
                              float4* __restrict__ prm)
{
    const int i = blockIdx.x * 256 + threadIdx.x;   // (b,c) pair
    if (i < NB * OCH) {
        const int b = i >> 4, c = i & 15;
        float s = 0.0f, q = 0.0f;
        for (int dd = 0; dd < OD; dd++) {
            s += stats[((b * OD + dd) * OCH + c) * 2 + 0];
            q += stats[((b * OD + dd) * OCH + c) * 2 + 1];
        }
        const float mean = s * (1.0f / (float)SPATIAL);
        float var = q * (1.0f / (float)SPATIAL) - mean * mean;
        var = fmaxf(var, 0.0f);
        const float rs = rsqrtf(var + EPSV);
        const float m  = mult[c];
        float4 p;
        p.x = rs * m;             // A
        p.y = -mean * rs * m;     // B
        p.z = -fabsf(m);          // L
        p.w =  fabsf(m);          // H
        prm[i] = p;
    }
}

// ===== norm_max (R1 version, measured ~11us = BW roofline; do not touch).
__global__ __launch_bounds__(256, 4) void norm_max_kernel(
    const unsigned short* __restrict__ y, const float4* __restrict__ prm,
    float* __restrict__ out)
{
    const int blk = blockIdx.x;     // NB*8 = 1024
    const int b   = blk >> 3;
    const int seg = blk & 7;
    const int tid = threadIdx.x;

    const int s = seg * 2048 + tid * 8;                  // 8 positions
    const unsigned short* yb = y + (size_t)b * OCH * SPATIAL + s;

    uint4 v[OCH];
#pragma unroll
    for (int c = 0; c < OCH; c++) {
        v[c] = *(const uint4*)(yb + (size_t)c * SPATIAL);
    }

    const float4* pb = prm + b * OCH;

    float mx[8];
#pragma unroll
    for (int j = 0; j < 8; j++) mx[j] = -INFINITY;

#pragma unroll
    for (int c = 0; c < OCH; c++) {
        const float4 p = pb[c];          // wave-uniform addr
        const float A = p.x, Bv = p.y, L = p.z, H = p.w;
        union { uint4 u4; unsigned int u[4]; } vv; vv.u4 = v[c];
#pragma unroll
        for (int w = 0; w < 4; w++) {
            union { unsigned int u; __fp16 h[2]; } a; a.u = vv.u[w];
            float f0 = fmaf((float)a.h[0], A, Bv);
            float f1 = fmaf((float)a.h[1], A, Bv);
            f0 = fminf(fmaxf(f0, L), H);                 // v_med3_f32 idiom
            f1 = fminf(fmaxf(f1, L), H);
            mx[2 * w]     = fmaxf(mx[2 * w],     f0);
            mx[2 * w + 1] = fmaxf(mx[2 * w + 1], f1);
        }
    }

    float* ob = out + (size_t)b * SPATIAL + s;
    float4 o0, o1;
    o0.x = mx[0]; o0.y = mx[1]; o0.z = mx[2]; o0.w = mx[3];
    o1.x = mx[4]; o1.y = mx[5]; o1.z = mx[6]; o1.w = mx[7];
    *(float4*)ob       = o0;
    *(float4*)(ob + 4) = o1;
}

extern "C" void kernel_launch(void* const* d_in, const int* in_sizes, int n_in,
                              void* d_out, int out_size, void* d_ws, size_t ws_size,
                              hipStream_t stream) {
    const float* x    = (const float*)d_in[0];
    const float* cw   = (const float*)d_in[1];
    const float* cb   = (const float*)d_in[2];
    const float* mult = (const float*)d_in[3];
    float* out = (float*)d_out;

    // ws: y fp16 channel-major (64 MB) | stats partials (256 KB) | prm (8 KB) | wp (2.7 KB)
    unsigned short* y = (unsigned short*)d_ws;
    float* stats = (float*)((char*)d_ws + (size_t)NB * OCH * SPATIAL * sizeof(unsigned short));
    float4* prm  = (float4*)(stats + NB * OD * OCH * 2);
    unsigned int* wpk = (unsigned int*)(prm + NB * OCH);

    transpose_w_kernel<<<3, 256, 0, stream>>>(cw, wpk);
    conv_stats_kernel<<<NB * 16, 256, 0, stream>>>(x, wpk, cb, mult, y, stats);
    params_kernel<<<8, 256, 0, stream>>>(stats, mult, prm);
    norm_max_kernel<<<NB * 8, 256, 0, stream>>>(y, prm, out);
}